// Round 1
// 105.226 us; speedup vs baseline: 1.0329x; 1.0329x over previous
//
#include <hip/hip_runtime.h>

// Block-sparse attention, fp16 QK + bf16 PV MFMA, deferred softmax,
// FUSED 2-way key split: one 512-thr WG (8 waves) per (qb, bh).
// This revision: pre-pass emits K/V tiles PRE-XOR-SWIZZLED + tile-contiguous in
// global; main kernel stages them with global_load_lds (16B DMA, no VGPR round
// trip) into DOUBLE-BUFFERED LDS -> one barrier per iteration. P tile is
// XOR-swizzled at stride 64 (<=2-way banks) so total LDS = 80 KB (2 WG/CU).
// fp32 in/out. B=2 H=8 S=2048 D=64, BLOCK=64, nb=32.

typedef __attribute__((ext_vector_type(8))) short short8;
typedef __attribute__((ext_vector_type(4))) short short4_;
typedef __attribute__((ext_vector_type(4))) float float4_;
typedef __attribute__((ext_vector_type(8))) _Float16 half8_;

#define B_   2
#define H_   8
#define S_   2048
#define D_   64
#define NB_  32
#define KP   72          // padded stride (fallback kernel only)
#define LOG2E 1.4426950408889634f

__device__ __forceinline__ short f2bf(float f) {            // RNE float->bf16 bits
    union { float f; unsigned int u; } x; x.f = f;
    unsigned int r = x.u + 0x7FFFu + ((x.u >> 16) & 1u);
    return (short)(r >> 16);
}
__device__ __forceinline__ short f2bf_t(float f) {          // truncating float->bf16
    union { float f; unsigned int u; } x; x.f = f;
    return (short)(x.u >> 16);
}
__device__ __forceinline__ float bf2f(short s) {
    union { unsigned int u; float f; } x; x.u = ((unsigned int)(unsigned short)s) << 16;
    return x.f;
}
__device__ __forceinline__ short f2h(float f) {
    _Float16 h = (_Float16)f;
    return __builtin_bit_cast(short, h);
}
// XOR-swizzled offset for a 64-col-short tile stored in granules of 8 shorts.
__device__ __forceinline__ int swz(int row, int gran) {
    return (row << 6) + (((gran ^ row) & 7) << 3);
}
// async global->LDS DMA, 16 B/lane, LDS dest = wave-uniform base + lane*16
__device__ __forceinline__ void gload16(const short* g, short* l) {
    __builtin_amdgcn_global_load_lds(
        (const __attribute__((address_space(1))) void*)g,
        (__attribute__((address_space(3))) void*)l, 16, 0, 0);
}

// ---------------- pre-pass: K -> fp16*log2e swizzled tiles, V -> transposed
// swizzled bf16 tiles. No LDS (4x4 register transpose). Tiles are contiguous
// 8 KB and byte-identical to the LDS image the main kernel wants, so
// global_load_lds can write LDS linearly. ----------------
__global__ __launch_bounds__(256)
void preconvert_kernel(const float* __restrict__ K, const float* __restrict__ V,
                       short* __restrict__ Khf, short* __restrict__ Vtb) {
    const int tid = threadIdx.x;
    const int kt  = blockIdx.x;                  // key tile 0..31
    const int bh  = blockIdx.y;                  // 0..15
    const size_t src = ((size_t)bh * S_ + kt * 64) * D_;    // fp32 source
    const size_t dst = ((size_t)(bh * NB_ + kt)) << 12;     // 4096-short tile

    // K: row-major, granule-swizzled within each 64-short row
#pragma unroll
    for (int it = 0; it < 4; ++it) {
        int i = tid + it * 256;
        int row = i >> 4, c4 = (i & 15) * 4;
        float4_ kv = *(const float4_*)(K + src + row * D_ + c4);
        short4_ kh;
#pragma unroll
        for (int e = 0; e < 4; ++e) kh[e] = f2h(kv[e] * LOG2E);   // fold log2e
        *(short4_*)(Khf + dst + swz(row, c4 >> 3) + (c4 & 7)) = kh;
    }

    // V: [d][key] transposed, granule-swizzled; 4x4 block per thread, no LDS
    {
        const int key4 = (tid >> 4) << 2;        // 0..60
        const int d4   = (tid & 15) << 2;        // 0..60  (lanes 0..15 coalesce a row)
        const float* vp = V + src + (size_t)key4 * D_ + d4;
        float4_ r0 = *(const float4_*)(vp);
        float4_ r1 = *(const float4_*)(vp + D_);
        float4_ r2 = *(const float4_*)(vp + 2 * D_);
        float4_ r3 = *(const float4_*)(vp + 3 * D_);
#pragma unroll
        for (int cc = 0; cc < 4; ++cc) {
            short4_ col;
            col[0] = f2bf(r0[cc]); col[1] = f2bf(r1[cc]);
            col[2] = f2bf(r2[cc]); col[3] = f2bf(r3[cc]);
            int d = d4 + cc;
            *(short4_*)(Vtb + dst + swz(d, key4 >> 3) + (key4 & 7)) = col;
        }
    }
}

// ---------------- main: 512-thr WG, fused 2-way key split, dbuf DMA staging ----------------
__global__ __launch_bounds__(512, 4)
void attn_fused(const float* __restrict__ Q,
                const float* __restrict__ Msk,
                const int* __restrict__ Mat,
                float* __restrict__ O,
                const short* __restrict__ Khf_g,
                const short* __restrict__ Vtb_g) {
    // shorts: K dbuf [buf][half][4096] @0 | V dbuf @16384 | P [wave][1024] @32768
    // total 40960 shorts = 80 KB -> 2 WGs/CU. Epilogue overlays as float.
    __shared__ __align__(16) short lds[40960];

    const int tid  = threadIdx.x;
    const int wave = tid >> 6;        // 0..7
    const int half = wave >> 2;       // key half 0/1
    const int w4   = wave & 3;        // wave within half; also 16-row q tile
    const int lane = tid & 63;
    const int c    = lane & 15;
    const int quad = lane >> 4;

    const int qb = blockIdx.x;        // 64-row q block 0..31
    const int bh = blockIdx.y;        // 0..15
    const int b  = bh / H_;
    const size_t base = (size_t)bh * S_ * D_;

    // ---- active-block bitmask; this half takes alternating entries ----
    unsigned long long bmv = __ballot(Mat[qb * NB_ + (lane & 31)] != 0);
    unsigned int mb = (unsigned int)(bmv & 0xFFFFFFFFull);
    const int nact  = __popc(mb);
    const int niter = (nact + 1) >> 1;    // identical for both halves (kill-padded)
    unsigned int mine = 0;
    {
        unsigned int tb2 = mb; int idx = 0;
        while (tb2) {
            int k = __builtin_ctz(tb2); tb2 &= tb2 - 1;
            if ((idx & 1) == half) mine |= (1u << k);
            ++idx;
        }
    }

    // ---- prologue: first tile (always a REAL block so LDS holds finite data) ----
    int kb; bool kill;
    if (mine) { kb = __builtin_ctz(mine); mine &= mine - 1; kill = false; }
    else      { kb = __builtin_ctz(mb); kill = true; }
    {
        const size_t tb = ((size_t)(bh * NB_ + kb)) << 12;
        const int kd = (half << 12) + (w4 << 10);           // buffer 0
        const short* gk = Khf_g + tb + (w4 << 10) + lane * 8;
        const short* gv = Vtb_g + tb + (w4 << 10) + lane * 8;
        gload16(gk,       &lds[kd]);
        gload16(gk + 512, &lds[kd + 512]);
        gload16(gv,       &lds[16384 + kd]);
        gload16(gv + 512, &lds[16384 + kd + 512]);
    }

    float biasc[4], biasn[4] = {0.f, 0.f, 0.f, 0.f};
#pragma unroll
    for (int t = 0; t < 4; ++t)
        biasc[t] = kill ? -2.0e6f
                        : -1.0e6f * LOG2E * (1.0f - Msk[(size_t)b * S_ + kb * 64 + t * 16 + c]);

    // ---- Q A-frags in fp16 (K carries the log2e scale) ----
    half8_ qa0, qa1;
    {
        const float* qp = Q + base + (size_t)(qb * 64 + w4 * 16 + c) * D_ + quad * 8;
        float4_ q0 = *(const float4_*)(qp);
        float4_ q1 = *(const float4_*)(qp + 4);
        float4_ q2 = *(const float4_*)(qp + 32);
        float4_ q3 = *(const float4_*)(qp + 36);
#pragma unroll
        for (int e = 0; e < 4; ++e) {
            qa0[e]     = (_Float16)q0[e];
            qa0[e + 4] = (_Float16)q1[e];
            qa1[e]     = (_Float16)q2[e];
            qa1[e + 4] = (_Float16)q3[e];
        }
    }

    float4_ o[4];
    float l_part[4];
#pragma unroll
    for (int t = 0; t < 4; ++t) { o[t][0] = 0.f; o[t][1] = 0.f; o[t][2] = 0.f; o[t][3] = 0.f; }
#pragma unroll
    for (int j = 0; j < 4; ++j) l_part[j] = 0.f;

    int foff_lo[4], foff_hi[4];
#pragma unroll
    for (int t = 0; t < 4; ++t) {
        foff_lo[t] = swz(t * 16 + c, quad);
        foff_hi[t] = swz(t * 16 + c, quad + 4);
    }
    const int pwoff = 32768 + (wave << 10);
    const int prd0  = pwoff + swz(c, quad);
    const int prd1  = pwoff + swz(c, quad + 4);

    int cur = 0;
    for (int it2 = 0; it2 < niter; ++it2) {
        // pick next tile (registers only; kb stays stale on kill -> refetch is safe)
        bool nkill = true;
        if (it2 + 1 < niter && mine) { kb = __builtin_ctz(mine); mine &= mine - 1; nkill = false; }

        __syncthreads();   // implicit vmcnt(0): tile it2 resident; buf cur^1 reusable

        if (it2 + 1 < niter) {
            const size_t tb = ((size_t)(bh * NB_ + kb)) << 12;
            const int kd = ((cur ^ 1) << 13) + (half << 12) + (w4 << 10);
            const short* gk = Khf_g + tb + (w4 << 10) + lane * 8;
            const short* gv = Vtb_g + tb + (w4 << 10) + lane * 8;
            gload16(gk,       &lds[kd]);
            gload16(gk + 512, &lds[kd + 512]);
            gload16(gv,       &lds[16384 + kd]);
            gload16(gv + 512, &lds[16384 + kd + 512]);
#pragma unroll
            for (int t = 0; t < 4; ++t)
                biasn[t] = nkill ? -2.0e6f
                                 : -1.0e6f * LOG2E * (1.0f - Msk[(size_t)b * S_ + kb * 64 + t * 16 + c]);
        }

        const int kbase = (cur << 13) + (half << 12);
        const int vbase = 16384 + kbase;

        // ---- scores (log2e-scaled): 8 fp16 MFMA from this half's K tile ----
        float4_ sc[4];
#pragma unroll
        for (int t = 0; t < 4; ++t) { sc[t][0] = 0.f; sc[t][1] = 0.f; sc[t][2] = 0.f; sc[t][3] = 0.f; }
        __builtin_amdgcn_s_setprio(1);
#pragma unroll
        for (int t = 0; t < 4; ++t) {
            half8_ kf0 = __builtin_bit_cast(half8_, *(const short8*)&lds[kbase + foff_lo[t]]);
            half8_ kf1 = __builtin_bit_cast(half8_, *(const short8*)&lds[kbase + foff_hi[t]]);
            sc[t] = __builtin_amdgcn_mfma_f32_16x16x32_f16(qa0, kf0, sc[t], 0, 0, 0);
            sc[t] = __builtin_amdgcn_mfma_f32_16x16x32_f16(qa1, kf1, sc[t], 0, 0, 0);
        }
        __builtin_amdgcn_s_setprio(0);

        // ---- P = exp2(s + bias'); per-lane l partial; P -> swizzled per-wave tile ----
#pragma unroll
        for (int t = 0; t < 4; ++t) {
            const int cg = (t << 1) + (c >> 3);      // column granule of t*16+c
#pragma unroll
            for (int j = 0; j < 4; ++j) {
                float p = __builtin_amdgcn_exp2f(sc[t][j] + biasc[t]);
                l_part[j] += p;
                const int row = quad * 4 + j;
                lds[pwoff + (row << 6) + (((cg ^ row) & 7) << 3) + (c & 7)] = f2bf_t(p);
            }
        }

        // ---- P A-frags (same-wave DS ordering) ----
        short8 pa0 = *(const short8*)&lds[prd0];
        short8 pa1 = *(const short8*)&lds[prd1];

        // ---- O += P * V (bf16) from this half's V tile ----
        __builtin_amdgcn_s_setprio(1);
#pragma unroll
        for (int t = 0; t < 4; ++t) {
            short8 vb0 = *(const short8*)&lds[vbase + foff_lo[t]];
            short8 vb1 = *(const short8*)&lds[vbase + foff_hi[t]];
            o[t] = __builtin_amdgcn_mfma_f32_16x16x32_bf16(pa0, vb0, o[t], 0, 0, 0);
            o[t] = __builtin_amdgcn_mfma_f32_16x16x32_bf16(pa1, vb1, o[t], 0, 0, 0);
        }
        __builtin_amdgcn_s_setprio(0);

#pragma unroll
        for (int t = 0; t < 4; ++t) biasc[t] = biasn[t];
        cur ^= 1;
    }

    // ---- in-LDS merge: half1 publishes (o, l); half0 adds, normalizes, stores ----
    __syncthreads();
    float* fl = (float*)lds;                  // overlays K/V/P area
    if (half == 1) {
        const int idx = ((wave - 4) * 64 + lane) * 21;   // 21-stride: conflict-free
#pragma unroll
        for (int t = 0; t < 4; ++t)
#pragma unroll
            for (int j = 0; j < 4; ++j) fl[idx + t * 4 + j] = o[t][j];
#pragma unroll
        for (int j = 0; j < 4; ++j) fl[idx + 16 + j] = l_part[j];
    }
    __syncthreads();
    if (half == 0) {
        const int idx = (wave * 64 + lane) * 21;
#pragma unroll
        for (int j = 0; j < 4; ++j) {
            float rs = l_part[j] + fl[idx + 16 + j];
            rs += __shfl_xor(rs, 1);
            rs += __shfl_xor(rs, 2);
            rs += __shfl_xor(rs, 4);
            rs += __shfl_xor(rs, 8);
            float inv = 1.0f / rs;
            size_t rowoff = base + (size_t)(qb * 64 + w4 * 16 + quad * 4 + j) * D_;
#pragma unroll
            for (int t = 0; t < 4; ++t)
                O[rowoff + t * 16 + c] = (o[t][j] + fl[idx + t * 4 + j]) * inv;
        }
    }
}

// ---------------- fallback (no workspace): bf16 hi/lo LDS-staging kernel ----------------
__global__ __launch_bounds__(256, 2)
void attn_mfma_fb(const float* __restrict__ Q,
                  const float* __restrict__ K,
                  const float* __restrict__ V,
                  const float* __restrict__ Msk,
                  const int* __restrict__ Mat,
                  float* __restrict__ O) {
    __shared__ __align__(16) short lds[4 * 64 * KP];
    short* Khi = lds;
    short* Klo = lds + 64 * KP;
    short* Vt  = lds + 2 * 64 * KP;
    short* Pl  = lds + 3 * 64 * KP;

    const int tid  = threadIdx.x;
    const int wave = tid >> 6;
    const int lane = tid & 63;
    const int c    = lane & 15;
    const int quad = lane >> 4;

    const int qb = blockIdx.x;
    const int bh = blockIdx.y;
    const int b  = bh / H_;
    const size_t base = (size_t)bh * S_ * D_;

    short8 qh0, qh1, ql0, ql1;
    {
        const float* qp = Q + base + (size_t)(qb * 64 + wave * 16 + c) * D_ + quad * 8;
#pragma unroll
        for (int e = 0; e < 8; ++e) {
            float f0 = qp[e], f1 = qp[e + 32];
            qh0[e] = f2bf(f0); ql0[e] = f2bf(f0 - bf2f(qh0[e]));
            qh1[e] = f2bf(f1); ql1[e] = f2bf(f1 - bf2f(qh1[e]));
        }
    }

    float4_ o[4];
    float l_part[4];
#pragma unroll
    for (int t = 0; t < 4; ++t) { o[t][0] = 0.f; o[t][1] = 0.f; o[t][2] = 0.f; o[t][3] = 0.f; }
#pragma unroll
    for (int j = 0; j < 4; ++j) l_part[j] = 0.f;

    for (int kb = 0; kb < NB_; ++kb) {
        if (Mat[qb * NB_ + kb] == 0) continue;

        __syncthreads();
        {
            const float* kg = K + base + (size_t)kb * 64 * D_;
            const float* vg = V + base + (size_t)kb * 64 * D_;
#pragma unroll
            for (int it = 0; it < 4; ++it) {
                int i = tid + it * 256;
                int row = i >> 4, c4 = (i & 15) * 4;
                float4_ kv = *(const float4_*)(kg + row * D_ + c4);
                short4_ hi, lo;
#pragma unroll
                for (int e = 0; e < 4; ++e) {
                    hi[e] = f2bf(kv[e]);
                    lo[e] = f2bf(kv[e] - bf2f(hi[e]));
                }
                *(short4_*)&Khi[row * KP + c4] = hi;
                *(short4_*)&Klo[row * KP + c4] = lo;
                float4_ vv = *(const float4_*)(vg + row * D_ + c4);
#pragma unroll
                for (int e = 0; e < 4; ++e) Vt[(c4 + e) * KP + row] = f2bf(vv[e]);
            }
        }
        __syncthreads();

        float4_ sc[4];
#pragma unroll
        for (int t = 0; t < 4; ++t) { sc[t][0] = 0.f; sc[t][1] = 0.f; sc[t][2] = 0.f; sc[t][3] = 0.f; }
#pragma unroll
        for (int t = 0; t < 4; ++t) {
            const short* kph = &Khi[(t * 16 + c) * KP + quad * 8];
            const short* kpl = &Klo[(t * 16 + c) * KP + quad * 8];
            short8 kh0 = *(const short8*)(kph);
            short8 kh1 = *(const short8*)(kph + 32);
            short8 kl0 = *(const short8*)(kpl);
            short8 kl1 = *(const short8*)(kpl + 32);
            sc[t] = __builtin_amdgcn_mfma_f32_16x16x32_bf16(qh0, kh0, sc[t], 0, 0, 0);
            sc[t] = __builtin_amdgcn_mfma_f32_16x16x32_bf16(qh1, kh1, sc[t], 0, 0, 0);
            sc[t] = __builtin_amdgcn_mfma_f32_16x16x32_bf16(qh0, kl0, sc[t], 0, 0, 0);
            sc[t] = __builtin_amdgcn_mfma_f32_16x16x32_bf16(qh1, kl1, sc[t], 0, 0, 0);
            sc[t] = __builtin_amdgcn_mfma_f32_16x16x32_bf16(ql0, kh0, sc[t], 0, 0, 0);
            sc[t] = __builtin_amdgcn_mfma_f32_16x16x32_bf16(ql1, kh1, sc[t], 0, 0, 0);
        }

        short* Pw = Pl + wave * 16 * KP;
#pragma unroll
        for (int t = 0; t < 4; ++t) {
            float bias = -1.0e6f * (1.0f - Msk[(size_t)b * S_ + kb * 64 + t * 16 + c]);
#pragma unroll
            for (int j = 0; j < 4; ++j) {
                float p = __expf(sc[t][j] + bias);
                l_part[j] += p;
                Pw[(quad * 4 + j) * KP + t * 16 + c] = f2bf(p);
            }
        }

        const short* pp = Pl + wave * 16 * KP + c * KP + quad * 8;
        short8 pa0 = *(const short8*)(pp);
        short8 pa1 = *(const short8*)(pp + 32);

#pragma unroll
        for (int t = 0; t < 4; ++t) {
            const short* vp = &Vt[(t * 16 + c) * KP + quad * 8];
            short8 vb0 = *(const short8*)(vp);
            short8 vb1 = *(const short8*)(vp + 32);
            o[t] = __builtin_amdgcn_mfma_f32_16x16x32_bf16(pa0, vb0, o[t], 0, 0, 0);
            o[t] = __builtin_amdgcn_mfma_f32_16x16x32_bf16(pa1, vb1, o[t], 0, 0, 0);
        }
    }

#pragma unroll
    for (int j = 0; j < 4; ++j) {
        float rs = l_part[j];
        rs += __shfl_xor(rs, 1);
        rs += __shfl_xor(rs, 2);
        rs += __shfl_xor(rs, 4);
        rs += __shfl_xor(rs, 8);
        float inv = 1.0f / rs;
        size_t rowoff = base + (size_t)(qb * 64 + wave * 16 + quad * 4 + j) * D_;
#pragma unroll
        for (int t = 0; t < 4; ++t)
            O[rowoff + t * 16 + c] = o[t][j] * inv;
    }
}

extern "C" void kernel_launch(void* const* d_in, const int* in_sizes, int n_in,
                              void* d_out, int out_size, void* d_ws, size_t ws_size,
                              hipStream_t stream) {
    const float* q   = (const float*)d_in[0];
    const float* k   = (const float*)d_in[1];
    const float* v   = (const float*)d_in[2];
    const float* msk = (const float*)d_in[3];
    const int*   mat = (const int*)d_in[4];
    float*       out = (float*)d_out;

    const size_t elems = (size_t)B_ * H_ * S_ * D_;      // 2,097,152
    const size_t need  = 2 * elems * sizeof(short);      // khf + vtb = 8.4 MB
    const int use_pre  = (ws_size >= need) ? 1 : 0;      // deterministic per-call

    short* khf = (short*)d_ws;
    short* vtb = khf + elems;

    if (use_pre) {
        dim3 pgrid(NB_, B_ * H_);
        preconvert_kernel<<<pgrid, dim3(256), 0, stream>>>(k, v, khf, vtb);
        dim3 grid(NB_, B_ * H_);                         // 32 x 16 = 512 WGs, 512 thr
        attn_fused<<<grid, dim3(512), 0, stream>>>(q, msk, mat, out, khf, vtb);
    } else {
        dim3 grid(NB_, B_ * H_);
        attn_mfma_fb<<<grid, dim3(256), 0, stream>>>(q, k, v, msk, mat, out);
    }
}

// Round 2
// 104.672 us; speedup vs baseline: 1.0384x; 1.0053x over previous
//
#include <hip/hip_runtime.h>

// Block-sparse attention, fp16 QK + bf16 PV MFMA, deferred softmax,
// FUSED 2-way key split: one 512-thr WG (8 waves) per (qb, bh).
// This revision:
//  - preconvert: V transposed via LDS with KP=66-short pad (max 4-way bank
//    conflict vs 16-way at 72) -> fully coalesced 128B swizzled tile writes.
//  - XCD-clustered WG remap (bijective, 512%8==0): XCD x owns bh {2x,2x+1} in
//    BOTH kernels, so each XCD's 1 MB tile set is produced and consumed in its
//    own L2 (was: every XCD streaming ~8 MB from L3).
// fp32 in/out. B=2 H=8 S=2048 D=64, BLOCK=64, nb=32.

typedef __attribute__((ext_vector_type(8))) short short8;
typedef __attribute__((ext_vector_type(4))) short short4_;
typedef __attribute__((ext_vector_type(4))) float float4_;
typedef __attribute__((ext_vector_type(8))) _Float16 half8_;

#define B_   2
#define H_   8
#define S_   2048
#define D_   64
#define NB_  32
#define KP   72          // padded stride (fallback kernel only)
#define KP2  66          // preconvert staging stride: 33 words -> conflict-light
#define LOG2E 1.4426950408889634f

__device__ __forceinline__ short f2bf(float f) {            // RNE float->bf16 bits
    union { float f; unsigned int u; } x; x.f = f;
    unsigned int r = x.u + 0x7FFFu + ((x.u >> 16) & 1u);
    return (short)(r >> 16);
}
__device__ __forceinline__ short f2bf_t(float f) {          // truncating float->bf16
    union { float f; unsigned int u; } x; x.f = f;
    return (short)(x.u >> 16);
}
__device__ __forceinline__ float bf2f(short s) {
    union { unsigned int u; float f; } x; x.u = ((unsigned int)(unsigned short)s) << 16;
    return x.f;
}
__device__ __forceinline__ short f2h(float f) {
    _Float16 h = (_Float16)f;
    return __builtin_bit_cast(short, h);
}
// XOR-swizzled offset for a 64-col-short tile stored in granules of 8 shorts.
__device__ __forceinline__ int swz(int row, int gran) {
    return (row << 6) + (((gran ^ row) & 7) << 3);
}
// async global->LDS DMA, 16 B/lane, LDS dest = wave-uniform base + lane*16
__device__ __forceinline__ void gload16(const short* g, short* l) {
    __builtin_amdgcn_global_load_lds(
        (const __attribute__((address_space(1))) void*)g,
        (__attribute__((address_space(3))) void*)l, 16, 0, 0);
}
// bijective XCD-clustering remap of a flat 512-WG id -> (bh, idx):
// XCD x (= n&7 under round-robin dispatch) owns bh {2x, 2x+1}, all 32 idx each.
__device__ __forceinline__ void wg_remap(int n, int& bh, int& idx) {
    const int xcd = n & 7;
    const int sub = n >> 3;          // 0..63
    bh  = (xcd << 1) + (sub & 1);
    idx = sub >> 1;                  // 0..31
}

// ---------------- pre-pass: K -> fp16*log2e swizzled tiles, V -> transposed
// swizzled bf16 tiles (LDS-staged, KP2 pad). Tiles are contiguous 8 KB and
// byte-identical to the LDS image the main kernel wants. ----------------
__global__ __launch_bounds__(256)
void preconvert_kernel(const float* __restrict__ K, const float* __restrict__ V,
                       short* __restrict__ Khf, short* __restrict__ Vtb) {
    __shared__ short vn[64 * KP2];               // natural bf16 V tile [key][d]
    const int tid = threadIdx.x;
    int bh, kt;
    wg_remap(blockIdx.x, bh, kt);
    const size_t src = ((size_t)bh * S_ + kt * 64) * D_;    // fp32 source
    const size_t dst = ((size_t)(bh * NB_ + kt)) << 12;     // 4096-short tile

    // phase 1: coalesced loads; K -> swizzled global rows, V -> LDS natural
#pragma unroll
    for (int it = 0; it < 4; ++it) {
        int i = tid + it * 256;
        int row = i >> 4, c4 = (i & 15) * 4;
        float4_ kv = *(const float4_*)(K + src + row * D_ + c4);
        short4_ kh;
#pragma unroll
        for (int e = 0; e < 4; ++e) kh[e] = f2h(kv[e] * LOG2E);   // fold log2e
        *(short4_*)(Khf + dst + swz(row, c4 >> 3) + (c4 & 7)) = kh;
        float4_ vv = *(const float4_*)(V + src + row * D_ + c4);
        short4_ vb;
#pragma unroll
        for (int e = 0; e < 4; ++e) vb[e] = f2bf(vv[e]);
        *(short4_*)&vn[row * KP2 + c4] = vb;
    }
    __syncthreads();

    // phase 2: transposed, swizzled, fully-coalesced tile writes
#pragma unroll
    for (int it = 0; it < 2; ++it) {
        int i = tid + it * 256;
        int d = i >> 3, g = i & 7;               // output granule (d-row, key-granule)
        short8 o;
#pragma unroll
        for (int e = 0; e < 8; ++e) o[e] = vn[(g * 8 + e) * KP2 + d];
        *(short8*)(Vtb + dst + swz(d, g)) = o;
    }
}

// ---------------- main: 512-thr WG, fused 2-way key split, dbuf DMA staging ----------------
__global__ __launch_bounds__(512, 4)
void attn_fused(const float* __restrict__ Q,
                const float* __restrict__ Msk,
                const int* __restrict__ Mat,
                float* __restrict__ O,
                const short* __restrict__ Khf_g,
                const short* __restrict__ Vtb_g) {
    // shorts: K dbuf [buf][half][4096] @0 | V dbuf @16384 | P [wave][1024] @32768
    // total 40960 shorts = 80 KB -> 2 WGs/CU. Epilogue overlays as float.
    __shared__ __align__(16) short lds[40960];

    const int tid  = threadIdx.x;
    const int wave = tid >> 6;        // 0..7
    const int half = wave >> 2;       // key half 0/1
    const int w4   = wave & 3;        // wave within half; also 16-row q tile
    const int lane = tid & 63;
    const int c    = lane & 15;
    const int quad = lane >> 4;

    int bh, qb;
    wg_remap(blockIdx.x, bh, qb);     // XCD-clustered: tiles L2-local
    const int b  = bh / H_;
    const size_t base = (size_t)bh * S_ * D_;

    // ---- active-block bitmask; this half takes alternating entries ----
    unsigned long long bmv = __ballot(Mat[qb * NB_ + (lane & 31)] != 0);
    unsigned int mb = (unsigned int)(bmv & 0xFFFFFFFFull);
    const int nact  = __popc(mb);
    const int niter = (nact + 1) >> 1;    // identical for both halves (kill-padded)
    unsigned int mine = 0;
    {
        unsigned int tb2 = mb; int idx = 0;
        while (tb2) {
            int k = __builtin_ctz(tb2); tb2 &= tb2 - 1;
            if ((idx & 1) == half) mine |= (1u << k);
            ++idx;
        }
    }

    // ---- prologue: first tile (always a REAL block so LDS holds finite data) ----
    int kb; bool kill;
    if (mine) { kb = __builtin_ctz(mine); mine &= mine - 1; kill = false; }
    else      { kb = __builtin_ctz(mb); kill = true; }
    {
        const size_t tb = ((size_t)(bh * NB_ + kb)) << 12;
        const int kd = (half << 12) + (w4 << 10);           // buffer 0
        const short* gk = Khf_g + tb + (w4 << 10) + lane * 8;
        const short* gv = Vtb_g + tb + (w4 << 10) + lane * 8;
        gload16(gk,       &lds[kd]);
        gload16(gk + 512, &lds[kd + 512]);
        gload16(gv,       &lds[16384 + kd]);
        gload16(gv + 512, &lds[16384 + kd + 512]);
    }

    float biasc[4], biasn[4] = {0.f, 0.f, 0.f, 0.f};
#pragma unroll
    for (int t = 0; t < 4; ++t)
        biasc[t] = kill ? -2.0e6f
                        : -1.0e6f * LOG2E * (1.0f - Msk[(size_t)b * S_ + kb * 64 + t * 16 + c]);

    // ---- Q A-frags in fp16 (K carries the log2e scale) ----
    half8_ qa0, qa1;
    {
        const float* qp = Q + base + (size_t)(qb * 64 + w4 * 16 + c) * D_ + quad * 8;
        float4_ q0 = *(const float4_*)(qp);
        float4_ q1 = *(const float4_*)(qp + 4);
        float4_ q2 = *(const float4_*)(qp + 32);
        float4_ q3 = *(const float4_*)(qp + 36);
#pragma unroll
        for (int e = 0; e < 4; ++e) {
            qa0[e]     = (_Float16)q0[e];
            qa0[e + 4] = (_Float16)q1[e];
            qa1[e]     = (_Float16)q2[e];
            qa1[e + 4] = (_Float16)q3[e];
        }
    }

    float4_ o[4];
    float l_part[4];
#pragma unroll
    for (int t = 0; t < 4; ++t) { o[t][0] = 0.f; o[t][1] = 0.f; o[t][2] = 0.f; o[t][3] = 0.f; }
#pragma unroll
    for (int j = 0; j < 4; ++j) l_part[j] = 0.f;

    int foff_lo[4], foff_hi[4];
#pragma unroll
    for (int t = 0; t < 4; ++t) {
        foff_lo[t] = swz(t * 16 + c, quad);
        foff_hi[t] = swz(t * 16 + c, quad + 4);
    }
    const int pwoff = 32768 + (wave << 10);
    const int prd0  = pwoff + swz(c, quad);
    const int prd1  = pwoff + swz(c, quad + 4);

    int cur = 0;
    for (int it2 = 0; it2 < niter; ++it2) {
        // pick next tile (registers only; kb stays stale on kill -> refetch is safe)
        bool nkill = true;
        if (it2 + 1 < niter && mine) { kb = __builtin_ctz(mine); mine &= mine - 1; nkill = false; }

        __syncthreads();   // implicit vmcnt(0): tile it2 resident; buf cur^1 reusable

        if (it2 + 1 < niter) {
            const size_t tb = ((size_t)(bh * NB_ + kb)) << 12;
            const int kd = ((cur ^ 1) << 13) + (half << 12) + (w4 << 10);
            const short* gk = Khf_g + tb + (w4 << 10) + lane * 8;
            const short* gv = Vtb_g + tb + (w4 << 10) + lane * 8;
            gload16(gk,       &lds[kd]);
            gload16(gk + 512, &lds[kd + 512]);
            gload16(gv,       &lds[16384 + kd]);
            gload16(gv + 512, &lds[16384 + kd + 512]);
#pragma unroll
            for (int t = 0; t < 4; ++t)
                biasn[t] = nkill ? -2.0e6f
                                 : -1.0e6f * LOG2E * (1.0f - Msk[(size_t)b * S_ + kb * 64 + t * 16 + c]);
        }

        const int kbase = (cur << 13) + (half << 12);
        const int vbase = 16384 + kbase;

        // ---- scores (log2e-scaled): 8 fp16 MFMA from this half's K tile ----
        float4_ sc[4];
#pragma unroll
        for (int t = 0; t < 4; ++t) { sc[t][0] = 0.f; sc[t][1] = 0.f; sc[t][2] = 0.f; sc[t][3] = 0.f; }
        __builtin_amdgcn_s_setprio(1);
#pragma unroll
        for (int t = 0; t < 4; ++t) {
            half8_ kf0 = __builtin_bit_cast(half8_, *(const short8*)&lds[kbase + foff_lo[t]]);
            half8_ kf1 = __builtin_bit_cast(half8_, *(const short8*)&lds[kbase + foff_hi[t]]);
            sc[t] = __builtin_amdgcn_mfma_f32_16x16x32_f16(qa0, kf0, sc[t], 0, 0, 0);
            sc[t] = __builtin_amdgcn_mfma_f32_16x16x32_f16(qa1, kf1, sc[t], 0, 0, 0);
        }
        __builtin_amdgcn_s_setprio(0);

        // ---- P = exp2(s + bias'); per-lane l partial; P -> swizzled per-wave tile ----
#pragma unroll
        for (int t = 0; t < 4; ++t) {
            const int cg = (t << 1) + (c >> 3);      // column granule of t*16+c
#pragma unroll
            for (int j = 0; j < 4; ++j) {
                float p = __builtin_amdgcn_exp2f(sc[t][j] + biasc[t]);
                l_part[j] += p;
                const int row = quad * 4 + j;
                lds[pwoff + (row << 6) + (((cg ^ row) & 7) << 3) + (c & 7)] = f2bf_t(p);
            }
        }

        // ---- P A-frags (same-wave DS ordering) ----
        short8 pa0 = *(const short8*)&lds[prd0];
        short8 pa1 = *(const short8*)&lds[prd1];

        // ---- O += P * V (bf16) from this half's V tile ----
        __builtin_amdgcn_s_setprio(1);
#pragma unroll
        for (int t = 0; t < 4; ++t) {
            short8 vb0 = *(const short8*)&lds[vbase + foff_lo[t]];
            short8 vb1 = *(const short8*)&lds[vbase + foff_hi[t]];
            o[t] = __builtin_amdgcn_mfma_f32_16x16x32_bf16(pa0, vb0, o[t], 0, 0, 0);
            o[t] = __builtin_amdgcn_mfma_f32_16x16x32_bf16(pa1, vb1, o[t], 0, 0, 0);
        }
        __builtin_amdgcn_s_setprio(0);

#pragma unroll
        for (int t = 0; t < 4; ++t) biasc[t] = biasn[t];
        cur ^= 1;
    }

    // ---- in-LDS merge: half1 publishes (o, l); half0 adds, normalizes, stores ----
    __syncthreads();
    float* fl = (float*)lds;                  // overlays K/V/P area
    if (half == 1) {
        const int idx = ((wave - 4) * 64 + lane) * 21;   // 21-stride: conflict-free
#pragma unroll
        for (int t = 0; t < 4; ++t)
#pragma unroll
            for (int j = 0; j < 4; ++j) fl[idx + t * 4 + j] = o[t][j];
#pragma unroll
        for (int j = 0; j < 4; ++j) fl[idx + 16 + j] = l_part[j];
    }
    __syncthreads();
    if (half == 0) {
        const int idx = (wave * 64 + lane) * 21;
#pragma unroll
        for (int j = 0; j < 4; ++j) {
            float rs = l_part[j] + fl[idx + 16 + j];
            rs += __shfl_xor(rs, 1);
            rs += __shfl_xor(rs, 2);
            rs += __shfl_xor(rs, 4);
            rs += __shfl_xor(rs, 8);
            float inv = 1.0f / rs;
            size_t rowoff = base + (size_t)(qb * 64 + w4 * 16 + quad * 4 + j) * D_;
#pragma unroll
            for (int t = 0; t < 4; ++t)
                O[rowoff + t * 16 + c] = (o[t][j] + fl[idx + t * 4 + j]) * inv;
        }
    }
}

// ---------------- fallback (no workspace): bf16 hi/lo LDS-staging kernel ----------------
__global__ __launch_bounds__(256, 2)
void attn_mfma_fb(const float* __restrict__ Q,
                  const float* __restrict__ K,
                  const float* __restrict__ V,
                  const float* __restrict__ Msk,
                  const int* __restrict__ Mat,
                  float* __restrict__ O) {
    __shared__ __align__(16) short lds[4 * 64 * KP];
    short* Khi = lds;
    short* Klo = lds + 64 * KP;
    short* Vt  = lds + 2 * 64 * KP;
    short* Pl  = lds + 3 * 64 * KP;

    const int tid  = threadIdx.x;
    const int wave = tid >> 6;
    const int lane = tid & 63;
    const int c    = lane & 15;
    const int quad = lane >> 4;

    const int qb = blockIdx.x;
    const int bh = blockIdx.y;
    const int b  = bh / H_;
    const size_t base = (size_t)bh * S_ * D_;

    short8 qh0, qh1, ql0, ql1;
    {
        const float* qp = Q + base + (size_t)(qb * 64 + wave * 16 + c) * D_ + quad * 8;
#pragma unroll
        for (int e = 0; e < 8; ++e) {
            float f0 = qp[e], f1 = qp[e + 32];
            qh0[e] = f2bf(f0); ql0[e] = f2bf(f0 - bf2f(qh0[e]));
            qh1[e] = f2bf(f1); ql1[e] = f2bf(f1 - bf2f(qh1[e]));
        }
    }

    float4_ o[4];
    float l_part[4];
#pragma unroll
    for (int t = 0; t < 4; ++t) { o[t][0] = 0.f; o[t][1] = 0.f; o[t][2] = 0.f; o[t][3] = 0.f; }
#pragma unroll
    for (int j = 0; j < 4; ++j) l_part[j] = 0.f;

    for (int kb = 0; kb < NB_; ++kb) {
        if (Mat[qb * NB_ + kb] == 0) continue;

        __syncthreads();
        {
            const float* kg = K + base + (size_t)kb * 64 * D_;
            const float* vg = V + base + (size_t)kb * 64 * D_;
#pragma unroll
            for (int it = 0; it < 4; ++it) {
                int i = tid + it * 256;
                int row = i >> 4, c4 = (i & 15) * 4;
                float4_ kv = *(const float4_*)(kg + row * D_ + c4);
                short4_ hi, lo;
#pragma unroll
                for (int e = 0; e < 4; ++e) {
                    hi[e] = f2bf(kv[e]);
                    lo[e] = f2bf(kv[e] - bf2f(hi[e]));
                }
                *(short4_*)&Khi[row * KP + c4] = hi;
                *(short4_*)&Klo[row * KP + c4] = lo;
                float4_ vv = *(const float4_*)(vg + row * D_ + c4);
#pragma unroll
                for (int e = 0; e < 4; ++e) Vt[(c4 + e) * KP + row] = f2bf(vv[e]);
            }
        }
        __syncthreads();

        float4_ sc[4];
#pragma unroll
        for (int t = 0; t < 4; ++t) { sc[t][0] = 0.f; sc[t][1] = 0.f; sc[t][2] = 0.f; sc[t][3] = 0.f; }
#pragma unroll
        for (int t = 0; t < 4; ++t) {
            const short* kph = &Khi[(t * 16 + c) * KP + quad * 8];
            const short* kpl = &Klo[(t * 16 + c) * KP + quad * 8];
            short8 kh0 = *(const short8*)(kph);
            short8 kh1 = *(const short8*)(kph + 32);
            short8 kl0 = *(const short8*)(kpl);
            short8 kl1 = *(const short8*)(kpl + 32);
            sc[t] = __builtin_amdgcn_mfma_f32_16x16x32_bf16(qh0, kh0, sc[t], 0, 0, 0);
            sc[t] = __builtin_amdgcn_mfma_f32_16x16x32_bf16(qh1, kh1, sc[t], 0, 0, 0);
            sc[t] = __builtin_amdgcn_mfma_f32_16x16x32_bf16(qh0, kl0, sc[t], 0, 0, 0);
            sc[t] = __builtin_amdgcn_mfma_f32_16x16x32_bf16(qh1, kl1, sc[t], 0, 0, 0);
            sc[t] = __builtin_amdgcn_mfma_f32_16x16x32_bf16(ql0, kh0, sc[t], 0, 0, 0);
            sc[t] = __builtin_amdgcn_mfma_f32_16x16x32_bf16(ql1, kh1, sc[t], 0, 0, 0);
        }

        short* Pw = Pl + wave * 16 * KP;
#pragma unroll
        for (int t = 0; t < 4; ++t) {
            float bias = -1.0e6f * (1.0f - Msk[(size_t)b * S_ + kb * 64 + t * 16 + c]);
#pragma unroll
            for (int j = 0; j < 4; ++j) {
                float p = __expf(sc[t][j] + bias);
                l_part[j] += p;
                Pw[(quad * 4 + j) * KP + t * 16 + c] = f2bf(p);
            }
        }

        const short* pp = Pl + wave * 16 * KP + c * KP + quad * 8;
        short8 pa0 = *(const short8*)(pp);
        short8 pa1 = *(const short8*)(pp + 32);

#pragma unroll
        for (int t = 0; t < 4; ++t) {
            const short* vp = &Vt[(t * 16 + c) * KP + quad * 8];
            short8 vb0 = *(const short8*)(vp);
            short8 vb1 = *(const short8*)(vp + 32);
            o[t] = __builtin_amdgcn_mfma_f32_16x16x32_bf16(pa0, vb0, o[t], 0, 0, 0);
            o[t] = __builtin_amdgcn_mfma_f32_16x16x32_bf16(pa1, vb1, o[t], 0, 0, 0);
        }
    }

#pragma unroll
    for (int j = 0; j < 4; ++j) {
        float rs = l_part[j];
        rs += __shfl_xor(rs, 1);
        rs += __shfl_xor(rs, 2);
        rs += __shfl_xor(rs, 4);
        rs += __shfl_xor(rs, 8);
        float inv = 1.0f / rs;
        size_t rowoff = base + (size_t)(qb * 64 + wave * 16 + quad * 4 + j) * D_;
#pragma unroll
        for (int t = 0; t < 4; ++t)
            O[rowoff + t * 16 + c] = o[t][j] * inv;
    }
}

extern "C" void kernel_launch(void* const* d_in, const int* in_sizes, int n_in,
                              void* d_out, int out_size, void* d_ws, size_t ws_size,
                              hipStream_t stream) {
    const float* q   = (const float*)d_in[0];
    const float* k   = (const float*)d_in[1];
    const float* v   = (const float*)d_in[2];
    const float* msk = (const float*)d_in[3];
    const int*   mat = (const int*)d_in[4];
    float*       out = (float*)d_out;

    const size_t elems = (size_t)B_ * H_ * S_ * D_;      // 2,097,152
    const size_t need  = 2 * elems * sizeof(short);      // khf + vtb = 8.4 MB
    const int use_pre  = (ws_size >= need) ? 1 : 0;      // deterministic per-call

    short* khf = (short*)d_ws;
    short* vtb = khf + elems;

    if (use_pre) {
        preconvert_kernel<<<dim3(NB_ * B_ * H_), dim3(256), 0, stream>>>(k, v, khf, vtb);
        attn_fused<<<dim3(NB_ * B_ * H_), dim3(512), 0, stream>>>(q, msk, mat, out, khf, vtb);
    } else {
        dim3 grid(NB_, B_ * H_);
        attn_mfma_fb<<<grid, dim3(256), 0, stream>>>(q, k, v, msk, mat, out);
    }
}